// Round 9
// baseline (556.765 us; speedup 1.0000x reference)
//
#include <hip/hip_runtime.h>
#include <math.h>

// Problem constants: b=2, h=16, s=4096, d=64, m=256
#define D 64
#define M 256
#define QOUT_ELEMS 33554432ull         // 2*16*4096*256 (q' flat size)

constexpr float DATA_NORM = 0.35355339059327373f;   // 64^-0.25
constexpr float L2E       = 1.4426950408889634f;    // log2(e)
constexpr float DN_L2E    = DATA_NORM * L2E;        // data_dash scale, log2 domain
constexpr float DIAG_L2E  = 0.0625f * L2E;          // 0.5*dn^2 * log2e
constexpr float RATIO     = 0.0625f;                // 256^-0.5
constexpr float EPS_F     = 1e-4f;

// ---------- K0: transpose projection [256][64] -> projT [64][256] in ws ----------
__global__ __launch_bounds__(256) void k0_transpose(const float* __restrict__ proj,
                                                    float* __restrict__ projT) {
    int i = blockIdx.x * 256 + threadIdx.x;   // 0..16383
    int m = i >> 6, d = i & 63;
    projT[d * M + m] = proj[i];
}

// ---------- K1: main fused matmul, projection held in REGISTERS ----------
// 512 threads (8 waves). Lane owns m-pair {mbase+2*lane, +1}; pr[64] = 128 VGPR.
// Waves 0-3: m 0..127, waves 4-7: m 128..255. Wave-pair (g, g+4) shares token
// group g (16 tokens/pass staged in LDS; matmul reads are same-address
// broadcasts only -> no per-lane LDS bandwidth).
// blocks 0..511: q (final q'); 512..1023: k (dd_l2e - diag_l2e; partial max).
__global__ __launch_bounds__(512, 2) void k1_main(
    const float* __restrict__ qin, const float* __restrict__ kin,
    const float* __restrict__ projT, float* __restrict__ out,
    float* __restrict__ partial_max)
{
    __shared__ float x_lds[4][16][D];      // 16 KB: [group][token][d]
    __shared__ float diag_lds[4][16];      // per-token diag (log2 domain)
    __shared__ float hm_lds[4][2][16];     // q: per-half per-token max
    __shared__ float wmax_lds[8];          // k: per-wave block max

    const int tid  = threadIdx.x;
    const int lane = tid & 63;
    const int wave = tid >> 6;
    const int grp  = wave & 3;             // token group
    const int half = wave >> 2;            // m-half
    const int bid  = blockIdx.x;
    const bool is_q = (bid < 512);
    const float* __restrict__ src = is_q ? qin : kin;
    const int tb = is_q ? bid : (bid - 512);
    float* __restrict__ outbase = out + (is_q ? 0ull : QOUT_ELEMS);

    // ---- load this lane's 2 projection columns into registers (one-time) ----
    float2 pr[D];                          // 128 VGPR
    {
        const float* pbase = projT + half * 128 + 2 * lane;   // coalesced f2
        #pragma unroll
        for (int d = 0; d < D; ++d)
            pr[d] = *(const float2*)(pbase + d * M);
    }

    float blockmax = -INFINITY;            // k only (log2 domain)

    for (int pass = 0; pass < 4; ++pass) {
        const int token0 = tb * 256 + pass * 64 + grp * 16;

        // ---- waves 0-3 stage 16 tokens (256 float4) + compute diag ----
        if (half == 0) {
            const float4* g = (const float4*)(src + (size_t)token0 * D);
            float4* xl = (float4*)(&x_lds[grp][0][0]);
            float4 xv[4];
            #pragma unroll
            for (int kk = 0; kk < 4; ++kk) xv[kk] = g[kk * 64 + lane];
            #pragma unroll
            for (int kk = 0; kk < 4; ++kk) xl[kk * 64 + lane] = xv[kk];
            // flat f4 idx kk*64+lane: token = kk*4 + (lane>>4), d4 = lane&15
            float ds_[4];
            #pragma unroll
            for (int kk = 0; kk < 4; ++kk)
                ds_[kk] = xv[kk].x*xv[kk].x + xv[kk].y*xv[kk].y
                        + xv[kk].z*xv[kk].z + xv[kk].w*xv[kk].w;
            #pragma unroll
            for (int off = 1; off < 16; off <<= 1) {
                #pragma unroll
                for (int kk = 0; kk < 4; ++kk)
                    ds_[kk] += __shfl_xor(ds_[kk], off);
            }
            if ((lane & 15) == 0) {
                #pragma unroll
                for (int kk = 0; kk < 4; ++kk)
                    diag_lds[grp][kk * 4 + (lane >> 4)] = ds_[kk] * DIAG_L2E;
            }
        }
        __syncthreads();   // x_lds + diag_lds visible

        // ---- matmul: acc[tt] = x[tt] . P[:, 2 lane-columns], all-register ----
        float2 acc[16];
        #pragma unroll
        for (int tt = 0; tt < 16; ++tt) acc[tt] = make_float2(0.f, 0.f);

        #pragma unroll
        for (int d4 = 0; d4 < 16; ++d4) {
            #pragma unroll
            for (int tt = 0; tt < 16; ++tt) {
                float4 xq = *(const float4*)&x_lds[grp][tt][4 * d4]; // broadcast
                acc[tt].x = fmaf(pr[4*d4+0].x, xq.x, acc[tt].x);
                acc[tt].y = fmaf(pr[4*d4+0].y, xq.x, acc[tt].y);
                acc[tt].x = fmaf(pr[4*d4+1].x, xq.y, acc[tt].x);
                acc[tt].y = fmaf(pr[4*d4+1].y, xq.y, acc[tt].y);
                acc[tt].x = fmaf(pr[4*d4+2].x, xq.z, acc[tt].x);
                acc[tt].y = fmaf(pr[4*d4+2].y, xq.z, acc[tt].y);
                acc[tt].x = fmaf(pr[4*d4+3].x, xq.w, acc[tt].x);
                acc[tt].y = fmaf(pr[4*d4+3].y, xq.w, acc[tt].y);
            }
        }

        // ---- epilogue ----
        if (is_q) {
            // per-token max over this wave's half of m, combine halves via LDS
            #pragma unroll
            for (int tt = 0; tt < 16; ++tt) {
                float hx = fmaxf(acc[tt].x, acc[tt].y) * DN_L2E;  // DN_L2E>0
                #pragma unroll
                for (int off = 1; off < 64; off <<= 1)
                    hx = fmaxf(hx, __shfl_xor(hx, off));
                if (lane == 0) hm_lds[grp][half][tt] = hx;
            }
            __syncthreads();   // hm_lds visible
            float2* ob2 = (float2*)outbase;
            #pragma unroll
            for (int tt = 0; tt < 16; ++tt) {
                const float stab = fmaxf(hm_lds[grp][0][tt], hm_lds[grp][1][tt]);
                const float c = diag_lds[grp][tt] + stab;
                float2 o;
                o.x = RATIO * (exp2f(acc[tt].x * DN_L2E - c) + EPS_F);
                o.y = RATIO * (exp2f(acc[tt].y * DN_L2E - c) + EPS_F);
                ob2[(size_t)(token0 + tt) * 128 + half * 64 + lane] = o;
            }
        } else {
            float2* ob2 = (float2*)outbase;
            #pragma unroll
            for (int tt = 0; tt < 16; ++tt) {
                const float ddx = acc[tt].x * DN_L2E;
                const float ddy = acc[tt].y * DN_L2E;
                blockmax = fmaxf(blockmax, fmaxf(ddx, ddy));
                const float dg = diag_lds[grp][tt];
                ob2[(size_t)(token0 + tt) * 128 + half * 64 + lane] =
                    make_float2(ddx - dg, ddy - dg);
            }
        }
        __syncthreads();   // protect x_lds/diag_lds/hm_lds before next pass
    }

    if (!is_q) {
        #pragma unroll
        for (int off = 1; off < 64; off <<= 1)
            blockmax = fmaxf(blockmax, __shfl_xor(blockmax, off));
        if (lane == 0) wmax_lds[wave] = blockmax;
        __syncthreads();
        if (tid == 0) {
            float m0 = -INFINITY;
            #pragma unroll
            for (int w = 0; w < 8; ++w) m0 = fmaxf(m0, wmax_lds[w]);
            partial_max[tb] = m0;
        }
    }
}

// ---------- K3: k' fix-up: out = ratio*(exp2(v - stab[bh]) + eps) ----------
__global__ __launch_bounds__(256) void k3_fix(float* __restrict__ outk,
                                              const float* __restrict__ partial) {
    const int bid = blockIdx.x;            // 2048 blocks, one (b,h)-64th each
    const int bh  = bid >> 6;              // 64 blocks per (b,h)
    const int tid = threadIdx.x;
    float v = partial[bh * 16 + (tid & 15)];
    #pragma unroll
    for (int off = 1; off < 16; off <<= 1)
        v = fmaxf(v, __shfl_xor(v, off));
    const float st = v;                    // uniform across lanes

    float4* p = (float4*)outk + (size_t)bid * 4096;
    #pragma unroll 4
    for (int it = 0; it < 16; ++it) {
        float4 w = p[it * 256 + tid];
        float4 o;
        o.x = RATIO * (exp2f(w.x - st) + EPS_F);
        o.y = RATIO * (exp2f(w.y - st) + EPS_F);
        o.z = RATIO * (exp2f(w.z - st) + EPS_F);
        o.w = RATIO * (exp2f(w.w - st) + EPS_F);
        p[it * 256 + tid] = o;
    }
}

extern "C" void kernel_launch(void* const* d_in, const int* in_sizes, int n_in,
                              void* d_out, int out_size, void* d_ws, size_t ws_size,
                              hipStream_t stream) {
    const float* q    = (const float*)d_in[0];
    const float* k    = (const float*)d_in[1];
    const float* proj = (const float*)d_in[2];
    float* out = (float*)d_out;
    float* ws  = (float*)d_ws;

    float* projT   = ws;                   // 16384 floats
    float* partial = ws + 16384;           // 512 floats

    k0_transpose<<<64,   256, 0, stream>>>(proj, projT);
    k1_main     <<<1024, 512, 0, stream>>>(q, k, projT, out, partial);
    k3_fix      <<<2048, 256, 0, stream>>>(out + QOUT_ELEMS, partial);
}